// Round 19
// baseline (41.851 us; speedup 1.0000x reference)
//
#include <hip/hip_runtime.h>
#include <hip/hip_fp16.h>

// AliasFreeActivation, round 19 (final tuning): r13 barrier-free wave-private
// structure (best wall: 39.15us) + filters via uniform SCALAR loads (SGPRs,
// removes 36 vector-load + 36 readfirstlane prologue per wave) +
// __launch_bounds__(256,8) to request full 8 waves/SIMD residency
// (VGPR=32, 16KB LDS/block -> 8 blocks/CU feasible).
// x (2,256,84,84) f32 -> up x4 (24t) -> lrelu -> down x2 (12t) -> crop 10
// -> out (2,256,148,148) f32.
//
// Unit = (plane pz, band b 0..9, chunk c 0..2) per wave64, private 1024-dw
// LDS slice, no __syncthreads. Band: out rows i0..i0+15, i0=min(16b,132)
// (band 9 overlaps band 8; duplicate stores bitwise-identical).
// Chunks: c0 g0..15 / out g8 0..6; c1 g14..29 / g8 7..13; c2 g28..38 / g8 14..18.
// LDS f16 layout: row r, 64 dwords; dword 4B+cc = half2(col 8B+cc, col 8B+4+cc).
// P2: lane-per-dword fused up-v+lrelu+down-v, v2 f32 math, lane-local alias
// (reads/writes its own 16 dwords: no cross-lane hazard).
// Cross-lane handoffs (P1->P2, P2->P3) ordered by s_waitcnt lgkmcnt(0).

typedef float v2 __attribute__((ext_vector_type(2)));

constexpr int IN_HW  = 84;
constexpr int OUT_HW = 148;
constexpr float SLOPE = 0.2f;

__device__ __forceinline__ unsigned pkv(v2 a) {
    __half2 h = __float22half2_rn(make_float2(a.x, a.y));
    union { __half2 h; unsigned u; } c; c.h = h; return c.u;
}
__device__ __forceinline__ v2 up16(unsigned u) {
    union { unsigned u; __half2 h; } c; c.u = u;
    float2 f = __half22float2(c.h);
    return (v2){f.x, f.y};
}
__device__ __forceinline__ void lds_fence() {
    asm volatile("s_waitcnt lgkmcnt(0)" ::: "memory");
}

template<int CHUNK>
__device__ __forceinline__ void wave_body(
    const float* __restrict__ xin, float* __restrict__ o,
    unsigned* __restrict__ S, int l, int i0, int IR0,
    const float* fu, const float* fd)
{
    constexpr int G0  = (CHUNK == 0) ? 0 : (CHUNK == 1) ? 14 : 28;
    constexpr int NG  = (CHUNK == 2) ? 11 : 16;   // input col-groups
    constexpr int GO8 = (CHUNK == 0) ? 0 : (CHUNK == 1) ? 7 : 14;
    constexpr int NG8 = (CHUNK == 2) ? 5 : 7;     // output col-groups
    constexpr int NT1 = 16 * NG;
    constexpr int NT3 = 16 * NG8;

    // ---- P1: horizontal up-conv into private LDS slice ----
#pragma unroll
    for (int k = 0; k < (NT1 + 63) / 64; ++k) {
        int t = l + 64 * k;
        if (t < NT1) {
            int r = t / NG, gl = t - r * NG, g = G0 + gl;
            const float* xr = xin + (IR0 + r) * IN_HW + 2 * g;
            float2 p0 = *(const float2*)(xr);
            float2 p1 = *(const float2*)(xr + 2);
            float2 p2 = *(const float2*)(xr + 4);
            float2 p3 = *(const float2*)(xr + 6);
            float2 p4 = *(const float2*)(xr + ((g == 38) ? 6 : 8)); // OOB guard
            v2 V0 = {p0.y, p1.x};
            v2 V1 = {p1.x, p1.y};
            v2 V2 = {p1.y, p2.x};
            v2 V3 = {p2.x, p2.y};
            v2 V4 = {p2.y, p3.x};
            v2 V5 = {p3.x, p3.y};
            v2 V6 = {p3.y, p4.x};   // .y garbage only for g=38 tail (unused cols)
            v2 AB0 = V5*fu[1] + V4*fu[5] + V3*fu[9]  + V2*fu[13] + V1*fu[17] + V0*fu[21];
            v2 AB1 = V5*fu[2] + V4*fu[6] + V3*fu[10] + V2*fu[14] + V1*fu[18] + V0*fu[22];
            v2 AB2 = V5*fu[3] + V4*fu[7] + V3*fu[11] + V2*fu[15] + V1*fu[19] + V0*fu[23];
            v2 AB3 = V6*fu[0] + V5*fu[4] + V4*fu[8]  + V3*fu[12] + V2*fu[16] + V1*fu[20];
            uint4 pk;
            pk.x = pkv(AB0); pk.y = pkv(AB1); pk.z = pkv(AB2); pk.w = pkv(AB3);
            *(uint4*)(S + r * 64 + 4 * gl) = pk;
        }
    }
    lds_fence();                       // P1 writes visible to all lanes

    // ---- P2: lane-per-dword fused up-v + lrelu + down-v (v2 f32) ----
    {
        const unsigned* up = S + l;
        v2 colv[16];
#pragma unroll
        for (int r = 0; r < 16; ++r) colv[r] = up16(up[r * 64]);
        v2 acc[16];
#pragma unroll
        for (int i = 0; i < 16; ++i) acc[i] = (v2)(0.0f);
#pragma unroll
        for (int t = 0; t < 42; ++t) {
            const int n  = (t + 1) >> 2;
            const int ph = (t + 1) & 3;
            v2 z = colv[n+5] * fu[ph];
            z += colv[n+4] * fu[ph+4];
            z += colv[n+3] * fu[ph+8];
            z += colv[n+2] * fu[ph+12];
            z += colv[n+1] * fu[ph+16];
            z += colv[n]   * fu[ph+20];
            z = __builtin_elementwise_max(z, z * SLOPE);   // lrelu
            const int m = t >> 1;
#pragma unroll
            for (int k = 0; k < 6; ++k) {                  // static after unroll
                const int li = m - k;
                if (li >= 0 && li < 16)
                    acc[li] += z * fd[(t & 1) ? (10 - 2*k) : (11 - 2*k)];
            }
        }
        unsigned* tvc = S + l;          // same dwords this lane read: no hazard
#pragma unroll
        for (int i = 0; i < 16; ++i) tvc[i * 64] = pkv(acc[i]);
    }
    lds_fence();                       // P2 writes visible to all lanes

    // ---- P3: horizontal down-conv + store ----
#pragma unroll
    for (int k = 0; k < 2; ++k) {
        int t = l + 64 * k;
        if (t < NT3) {
            int i = t / NG8, gl8 = t - i * NG8;
            const unsigned* base = S + i * 64 + 8 * gl8;
            unsigned d[14];
            *(uint4*)&d[0]  = *(const uint4*)(base);
            *(uint4*)&d[4]  = *(const uint4*)(base + 4);
            *(uint4*)&d[8]  = *(const uint4*)(base + 8);
            *(uint2*)&d[12] = *(const uint2*)(base + 12);
            float W[26];
#pragma unroll
            for (int c = 0; c < 26; ++c) {
                const int D = ((c >> 3) << 2) + (c & 3);
                v2 f = up16(d[D]);
                W[c] = ((c >> 2) & 1) ? f.y : f.x;
            }
            v2 U[18];                                // U[t] = (col t, col t+8)
#pragma unroll
            for (int u = 0; u < 18; ++u)
                U[u] = (v2){ W[u], W[u + 8] };
            v2 q[4];
#pragma unroll
            for (int m = 0; m < 4; ++m) {
                v2 a = U[2 * m + 11] * fd[0];
#pragma unroll
                for (int u = 1; u < 12; ++u)
                    a += U[2 * m + 11 - u] * fd[u];
                q[m] = a;
            }
            const int g8g = GO8 + gl8;
            float* orow = o + (size_t)(i0 + i) * OUT_HW + 8 * g8g;
            *(float4*)(orow) = make_float4(q[0].x, q[1].x, q[2].x, q[3].x);
            if (g8g < 18)
                *(float4*)(orow + 4) = make_float4(q[0].y, q[1].y, q[2].y, q[3].y);
        }
    }
}

__global__ __launch_bounds__(256, 8) void afa_wave(
    const float* __restrict__ x, const float* __restrict__ ku,
    const float* __restrict__ kd, float* __restrict__ out)
{
    __shared__ __align__(16) unsigned sb[4 * 1024];    // 16 KB: 4 wave slices
    const int lt = threadIdx.x;
    const int w  = lt >> 6;
    const int l  = lt & 63;
    unsigned* S = sb + (w << 10);

    const int unit = blockIdx.x * 4 + w;               // 0..15359
    const int pz   = unit / 30;
    const int rem  = unit - 30 * pz;
    const int band = rem / 3;
    const int chunk = rem - 3 * band;
    const int i0   = (band == 9) ? 132 : 16 * band;
    const int IR0  = (i0 >> 1) + 1;

    // Uniform addresses -> scalar loads; filters live in SGPRs (no vector
    // load + readfirstlane prologue).
    float fu[24], fd[12];
#pragma unroll
    for (int i = 0; i < 24; ++i) fu[i] = ku[i];
#pragma unroll
    for (int i = 0; i < 12; ++i) fd[i] = kd[i];

    const float* xin = x + (size_t)pz * (IN_HW * IN_HW);
    float* o = out + (size_t)pz * (OUT_HW * OUT_HW);

    if (chunk == 0)      wave_body<0>(xin, o, S, l, i0, IR0, fu, fd);
    else if (chunk == 1) wave_body<1>(xin, o, S, l, i0, IR0, fu, fd);
    else                 wave_body<2>(xin, o, S, l, i0, IR0, fu, fd);
}

extern "C" void kernel_launch(void* const* d_in, const int* in_sizes, int n_in,
                              void* d_out, int out_size, void* d_ws, size_t ws_size,
                              hipStream_t stream) {
    const float* x  = (const float*)d_in[0];
    const float* ku = (const float*)d_in[1];
    const float* kd = (const float*)d_in[2];
    float* out = (float*)d_out;
    afa_wave<<<dim3(3840), dim3(256), 0, stream>>>(x, ku, kd, out);
}

// Round 20
// 38.853 us; speedup vs baseline: 1.0772x; 1.0772x over previous
//
#include <hip/hip_runtime.h>
#include <hip/hip_fp16.h>

// AliasFreeActivation, FINAL (= round 13, the session's best: 39.15us wall).
// x (2,256,84,84) f32 -> up x4 (24t) -> lrelu -> down x2 (12t) -> crop 10
// -> out (2,256,148,148) f32.
//
// Unit = (plane pz, band b in 0..9, chunk c in 0..2) handled by ONE wave64
// with a private 1024-dword LDS slice; NO __syncthreads anywhere.
// Band: out rows i0..i0+15, i0=min(16b,132) (band 9 overlaps band 8;
// duplicate stores bitwise-identical). z rows s=0..41 (ZR0=2*i0+15, ≡3 mod 4).
// Chunks (z-col groups g of 8 cols; out-col groups g8 of 8):
//   c0: g 0..15   (z cols   0..127), g8  0..6  (out   0..55)
//   c1: g 14..29  (z cols 112..239), g8  7..13 (out  56..111)
//   c2: g 28..38  (z cols 224..311), g8 14..18 (out 112..147; g8=18 partial)
// LDS slice layout (f16): row r in 0..15, 64 dwords/row; per 8-col block B
// dword 4B+cc = __half2(col 8B+cc, col 8B+4+cc).
// P1: task (r, gl): global float2 window reads -> 24 pk-fma -> uint4 store.
// P2: lane d owns dword-column d: 16 ds_reads (2-way banks = free), 42-step
//     fused up-v+lrelu+down-v in v2 f32, writes tv to the SAME 16 dwords
//     (lane-local alias: no cross-lane hazard, no sync needed).
// P3: task (i, gl8): 14 dword reads of row i -> unpack -> 48 pk-fma -> 2
//     float4 global stores. Cross-lane LDS handoffs (P1->P2, P2->P3) are
//     ordered by explicit s_waitcnt lgkmcnt(0) within the wave.
//
// Session notes (why this shape): barrier-phased block structures plateau at
// ~50% VALU issue; f16 LDS keeps column reads 2-way conflict-free; filters
// via per-wave vector load + readfirstlane (scalar-load variant + 8-wave
// launch_bounds regressed via L2 write thrash, r19). Tested-null levers:
// persistence, LDS bytes, MFMA offload, load-hoisting, remat pinning, f32 LDS.

typedef float v2 __attribute__((ext_vector_type(2)));

constexpr int IN_HW  = 84;
constexpr int OUT_HW = 148;
constexpr float SLOPE = 0.2f;

__device__ __forceinline__ float rfl(float v) {
    return __uint_as_float(__builtin_amdgcn_readfirstlane(__float_as_uint(v)));
}
__device__ __forceinline__ unsigned pkv(v2 a) {
    __half2 h = __float22half2_rn(make_float2(a.x, a.y));
    union { __half2 h; unsigned u; } c; c.h = h; return c.u;
}
__device__ __forceinline__ v2 up16(unsigned u) {
    union { unsigned u; __half2 h; } c; c.u = u;
    float2 f = __half22float2(c.h);
    return (v2){f.x, f.y};
}
__device__ __forceinline__ void lds_fence() {
    asm volatile("s_waitcnt lgkmcnt(0)" ::: "memory");
}

template<int CHUNK>
__device__ __forceinline__ void wave_body(
    const float* __restrict__ xin, float* __restrict__ o,
    unsigned* __restrict__ S, int l, int i0, int IR0,
    const float* fu, const float* fd)
{
    constexpr int G0  = (CHUNK == 0) ? 0 : (CHUNK == 1) ? 14 : 28;
    constexpr int NG  = (CHUNK == 2) ? 11 : 16;   // input col-groups
    constexpr int GO8 = (CHUNK == 0) ? 0 : (CHUNK == 1) ? 7 : 14;
    constexpr int NG8 = (CHUNK == 2) ? 5 : 7;     // output col-groups
    constexpr int NT1 = 16 * NG;
    constexpr int NT3 = 16 * NG8;

    // ---- P1: horizontal up-conv into private LDS slice ----
#pragma unroll
    for (int k = 0; k < (NT1 + 63) / 64; ++k) {
        int t = l + 64 * k;
        if (t < NT1) {
            int r = t / NG, gl = t - r * NG, g = G0 + gl;
            const float* xr = xin + (IR0 + r) * IN_HW + 2 * g;
            float2 p0 = *(const float2*)(xr);
            float2 p1 = *(const float2*)(xr + 2);
            float2 p2 = *(const float2*)(xr + 4);
            float2 p3 = *(const float2*)(xr + 6);
            float2 p4 = *(const float2*)(xr + ((g == 38) ? 6 : 8)); // OOB guard
            v2 V0 = {p0.y, p1.x};
            v2 V1 = {p1.x, p1.y};
            v2 V2 = {p1.y, p2.x};
            v2 V3 = {p2.x, p2.y};
            v2 V4 = {p2.y, p3.x};
            v2 V5 = {p3.x, p3.y};
            v2 V6 = {p3.y, p4.x};   // .y garbage only for g=38 tail (unused cols)
            v2 AB0 = V5*fu[1] + V4*fu[5] + V3*fu[9]  + V2*fu[13] + V1*fu[17] + V0*fu[21];
            v2 AB1 = V5*fu[2] + V4*fu[6] + V3*fu[10] + V2*fu[14] + V1*fu[18] + V0*fu[22];
            v2 AB2 = V5*fu[3] + V4*fu[7] + V3*fu[11] + V2*fu[15] + V1*fu[19] + V0*fu[23];
            v2 AB3 = V6*fu[0] + V5*fu[4] + V4*fu[8]  + V3*fu[12] + V2*fu[16] + V1*fu[20];
            uint4 pk;
            pk.x = pkv(AB0); pk.y = pkv(AB1); pk.z = pkv(AB2); pk.w = pkv(AB3);
            *(uint4*)(S + r * 64 + 4 * gl) = pk;
        }
    }
    lds_fence();                       // P1 writes visible to all lanes

    // ---- P2: lane-per-dword fused up-v + lrelu + down-v (v2 f32) ----
    {
        const unsigned* up = S + l;
        v2 colv[16];
#pragma unroll
        for (int r = 0; r < 16; ++r) colv[r] = up16(up[r * 64]);
        v2 acc[16];
#pragma unroll
        for (int i = 0; i < 16; ++i) acc[i] = (v2)(0.0f);
#pragma unroll
        for (int t = 0; t < 42; ++t) {
            const int n  = (t + 1) >> 2;
            const int ph = (t + 1) & 3;
            v2 z = colv[n+5] * fu[ph];
            z += colv[n+4] * fu[ph+4];
            z += colv[n+3] * fu[ph+8];
            z += colv[n+2] * fu[ph+12];
            z += colv[n+1] * fu[ph+16];
            z += colv[n]   * fu[ph+20];
            z = __builtin_elementwise_max(z, z * SLOPE);   // lrelu
            const int m = t >> 1;
#pragma unroll
            for (int k = 0; k < 6; ++k) {                  // static after unroll
                const int li = m - k;
                if (li >= 0 && li < 16)
                    acc[li] += z * fd[(t & 1) ? (10 - 2*k) : (11 - 2*k)];
            }
        }
        unsigned* tvc = S + l;          // same dwords this lane read: no hazard
#pragma unroll
        for (int i = 0; i < 16; ++i) tvc[i * 64] = pkv(acc[i]);
    }
    lds_fence();                       // P2 writes visible to all lanes

    // ---- P3: horizontal down-conv + store ----
#pragma unroll
    for (int k = 0; k < 2; ++k) {
        int t = l + 64 * k;
        if (t < NT3) {
            int i = t / NG8, gl8 = t - i * NG8;
            const unsigned* base = S + i * 64 + 8 * gl8;
            unsigned d[14];
            *(uint4*)&d[0]  = *(const uint4*)(base);
            *(uint4*)&d[4]  = *(const uint4*)(base + 4);
            *(uint4*)&d[8]  = *(const uint4*)(base + 8);
            *(uint2*)&d[12] = *(const uint2*)(base + 12);
            float W[26];
#pragma unroll
            for (int c = 0; c < 26; ++c) {
                const int D = ((c >> 3) << 2) + (c & 3);
                v2 f = up16(d[D]);
                W[c] = ((c >> 2) & 1) ? f.y : f.x;
            }
            v2 U[18];                                // U[t] = (col t, col t+8)
#pragma unroll
            for (int u = 0; u < 18; ++u)
                U[u] = (v2){ W[u], W[u + 8] };
            v2 q[4];
#pragma unroll
            for (int m = 0; m < 4; ++m) {
                v2 a = U[2 * m + 11] * fd[0];
#pragma unroll
                for (int u = 1; u < 12; ++u)
                    a += U[2 * m + 11 - u] * fd[u];
                q[m] = a;
            }
            const int g8g = GO8 + gl8;
            float* orow = o + (size_t)(i0 + i) * OUT_HW + 8 * g8g;
            *(float4*)(orow) = make_float4(q[0].x, q[1].x, q[2].x, q[3].x);
            if (g8g < 18)
                *(float4*)(orow + 4) = make_float4(q[0].y, q[1].y, q[2].y, q[3].y);
        }
    }
}

__global__ __launch_bounds__(256) void afa_wave(
    const float* __restrict__ x, const float* __restrict__ ku,
    const float* __restrict__ kd, float* __restrict__ out)
{
    __shared__ __align__(16) unsigned sb[4 * 1024];    // 16 KB: 4 wave slices
    const int lt = threadIdx.x;
    const int w  = lt >> 6;
    const int l  = lt & 63;
    unsigned* S = sb + (w << 10);

    const int unit = blockIdx.x * 4 + w;               // 0..15359
    const int pz   = unit / 30;
    const int rem  = unit - 30 * pz;
    const int band = rem / 3;
    const int chunk = rem - 3 * band;
    const int i0   = (band == 9) ? 132 : 16 * band;
    const int IR0  = (i0 >> 1) + 1;

    float fu[24], fd[12];
#pragma unroll
    for (int i = 0; i < 24; ++i) fu[i] = rfl(ku[i]);
#pragma unroll
    for (int i = 0; i < 12; ++i) fd[i] = rfl(kd[i]);

    const float* xin = x + (size_t)pz * (IN_HW * IN_HW);
    float* o = out + (size_t)pz * (OUT_HW * OUT_HW);

    if (chunk == 0)      wave_body<0>(xin, o, S, l, i0, IR0, fu, fd);
    else if (chunk == 1) wave_body<1>(xin, o, S, l, i0, IR0, fu, fd);
    else                 wave_body<2>(xin, o, S, l, i0, IR0, fu, fd);
}

extern "C" void kernel_launch(void* const* d_in, const int* in_sizes, int n_in,
                              void* d_out, int out_size, void* d_ws, size_t ws_size,
                              hipStream_t stream) {
    const float* x  = (const float*)d_in[0];
    const float* ku = (const float*)d_in[1];
    const float* kd = (const float*)d_in[2];
    float* out = (float*)d_out;
    afa_wave<<<dim3(3840), dim3(256), 0, stream>>>(x, ku, kd, out);
}